// Round 1
// baseline (1875.125 us; speedup 1.0000x reference)
//
#include <hip/hip_runtime.h>
#include <math.h>

// Problem constants (fixed by reference)
#define TT 8
#define NTOK 32768
#define DD 128
#define LCOMP 8
#define GSZ 8192          // N_ENTIRE / COMP_LEN
#define CDIM 64
#define EDIM 128          // 2*COMP_DIM
#define NBINS (TT*LCOMP)  // 64
#define BLOCKS_PER_BIN 16

// workspace offsets (bytes)
#define O_CNT   0                       // 64 ints
#define O_LIST  1024                    // 64*8192 ints = 2 MiB
#define O_CSUM  (O_LIST + 64*8192*4)    // 8*8*64 floats = 16 KiB
#define O_CZERO (O_CSUM + 16384)        // 64 floats
#define O_W1T   (O_CZERO + 1024)        // 128*128 floats = 64 KiB

__device__ __forceinline__ float gelu_exact(float a) {
    return 0.5f * a * (1.0f + erff(a * 0.70710678118654752f));
}

// ---------------- binning: token -> (t, group) list ----------------
__global__ void bin_kernel(const int* __restrict__ node_idx,
                           int* __restrict__ cnt, int* __restrict__ list) {
    int gid = blockIdx.x * blockDim.x + threadIdx.x;
    if (gid >= TT * NTOK) return;
    int t = gid >> 15;          // / NTOK
    int i = gid & (NTOK - 1);
    int l = node_idx[gid] >> 13; // / GSZ
    int bin = t * LCOMP + l;
    int pos = atomicAdd(&cnt[bin], 1);
    list[bin * GSZ + pos] = i;
}

// ---------------- prep: transpose w1, compute c_zero ----------------
__global__ void prep_kernel(const float* __restrict__ w1, const float* __restrict__ b1,
                            const float* __restrict__ w2,
                            float* __restrict__ w1t, float* __restrict__ czero) {
    int tid = blockIdx.x * 256 + threadIdx.x;
    if (tid < DD * EDIM) {
        int d = tid >> 7, j = tid & 127;
        w1t[j * DD + d] = w1[d * EDIM + j];
    }
    if (blockIdx.x == 0 && threadIdx.x < CDIM) {
        float acc = 0.f;
        for (int dd = 0; dd < EDIM; ++dd) {
            float hb = gelu_exact(b1[dd]);
            acc += hb * w2[dd * CDIM + threadIdx.x];
        }
        czero[threadIdx.x] = acc;
    }
}

// ---------------- main: fused LN + MLP + group-sum ----------------
__global__ __launch_bounds__(256)
void main_kernel(const float* __restrict__ x,
                 const float* __restrict__ ln1w, const float* __restrict__ ln1b,
                 const float* __restrict__ w1t, const float* __restrict__ b1,
                 const float* __restrict__ w2,
                 const int* __restrict__ cnt, const int* __restrict__ list,
                 float* __restrict__ csum) {
    int bin = blockIdx.x / BLOCKS_PER_BIN;
    int sub = blockIdx.x % BLOCKS_PER_BIN;
    int t = bin >> 3;
    int n = cnt[bin];
    const int* mylist = list + bin * GSZ;

    float acc[CDIM];
#pragma unroll
    for (int k = 0; k < CDIM; ++k) acc[k] = 0.f;

    for (int p = sub * 256 + threadIdx.x; p < n; p += BLOCKS_PER_BIN * 256) {
        int i = mylist[p];
        const float* xp = x + ((size_t)t * NTOK + i) * DD;
        float v[DD];
#pragma unroll
        for (int d = 0; d < DD; d += 4) {
            float4 f = *reinterpret_cast<const float4*>(xp + d);
            v[d] = f.x; v[d + 1] = f.y; v[d + 2] = f.z; v[d + 3] = f.w;
        }
        // LayerNorm (4-way split accumulators to break dep chains)
        float s0 = 0.f, s1 = 0.f, s2 = 0.f, s3 = 0.f;
        float q0 = 0.f, q1 = 0.f, q2 = 0.f, q3 = 0.f;
#pragma unroll
        for (int d = 0; d < DD; d += 4) {
            s0 += v[d];     q0 += v[d] * v[d];
            s1 += v[d + 1]; q1 += v[d + 1] * v[d + 1];
            s2 += v[d + 2]; q2 += v[d + 2] * v[d + 2];
            s3 += v[d + 3]; q3 += v[d + 3] * v[d + 3];
        }
        float s = (s0 + s1) + (s2 + s3);
        float q = (q0 + q1) + (q2 + q3);
        float m = s * (1.f / DD);
        float var = q * (1.f / DD) - m * m;
        float rs = rsqrtf(var + 1e-5f);
#pragma unroll
        for (int d = 0; d < DD; ++d)
            v[d] = (v[d] - m) * rs * ln1w[d] + ln1b[d];

        // MLP: h_j = gelu(xn . w1[:,j] + b1[j]); acc += h_j * w2[j,:]
        for (int j = 0; j < EDIM; ++j) {
            const float* wr = w1t + j * DD;   // uniform -> scalar loads
            float a0 = 0.f, a1 = 0.f, a2 = 0.f, a3 = 0.f;
#pragma unroll
            for (int d = 0; d < DD; d += 4) {
                a0 += v[d] * wr[d];
                a1 += v[d + 1] * wr[d + 1];
                a2 += v[d + 2] * wr[d + 2];
                a3 += v[d + 3] * wr[d + 3];
            }
            float a = ((a0 + a1) + (a2 + a3)) + b1[j];
            float h = gelu_exact(a);
            const float* w2r = w2 + j * CDIM; // uniform -> scalar loads
#pragma unroll
            for (int k = 0; k < CDIM; ++k) acc[k] += h * w2r[k];
        }
    }

    // wave butterfly reduce: lane k ends with the wave-total of acc[k]
    int lane = threadIdx.x & 63;
    float mine = 0.f;
#pragma unroll
    for (int k = 0; k < CDIM; ++k) {
        float val = acc[k];
#pragma unroll
        for (int off = 32; off > 0; off >>= 1) val += __shfl_xor(val, off, 64);
        if (lane == k) mine = val;
    }
    atomicAdd(&csum[bin * CDIM + lane], mine);
}

// ---------------- finalize: comp, LN(512), ortho loss ----------------
__global__ void fin_kernel(const float* __restrict__ csum, const int* __restrict__ cnt,
                           const float* __restrict__ czero, const float* __restrict__ b2,
                           const float* __restrict__ lnfw, const float* __restrict__ lnfb,
                           float* __restrict__ out) {
    __shared__ float comp[TT * LCOMP * CDIM]; // 4096 floats
    __shared__ float norm_s[LCOMP], sum_s[LCOMP], red[8];
    int tid = threadIdx.x;

    for (int idx = tid; idx < TT * LCOMP * CDIM; idx += 512) {
        int t = idx >> 9;
        int lk = idx & 511;
        int l = lk >> 6;
        int k = lk & 63;
        float nz = (float)(GSZ - cnt[t * LCOMP + l]);
        comp[idx] = (csum[idx] + nz * czero[k]) * (1.f / GSZ) + b2[k];
    }
    __syncthreads();

    int wave = tid >> 6, lane = tid & 63;

    // per-t LayerNorm over 512 -> out[t*512 + e]
    {
        int t = wave; // 8 waves, one per t
        float s = 0.f, q = 0.f;
        for (int e = lane; e < 512; e += 64) {
            float v = comp[t * 512 + e];
            s += v; q += v * v;
        }
#pragma unroll
        for (int off = 32; off > 0; off >>= 1) {
            s += __shfl_xor(s, off, 64);
            q += __shfl_xor(q, off, 64);
        }
        float m = s * (1.f / 512.f);
        float var = q * (1.f / 512.f) - m * m;
        float rs = rsqrtf(var + 1e-5f);
        for (int e = lane; e < 512; e += 64) {
            float v = comp[t * 512 + e];
            out[t * 512 + e] = (v - m) * rs * lnfw[e] + lnfb[e];
        }
    }

    // per-l norm and sum of f[l][t*64+k] = comp[t][l][k]
    {
        int l = wave;
        float s2 = 0.f, s1 = 0.f;
        for (int qd = lane; qd < 512; qd += 64) {
            int t = qd >> 6, k = qd & 63;
            float v = comp[t * 512 + l * 64 + k];
            s2 += v * v; s1 += v;
        }
#pragma unroll
        for (int off = 32; off > 0; off >>= 1) {
            s2 += __shfl_xor(s2, off, 64);
            s1 += __shfl_xor(s1, off, 64);
        }
        if (lane == 0) { norm_s[l] = sqrtf(s2); sum_s[l] = s1; }
    }
    __syncthreads();

    // 49 pairs (i in 0..6, j in 1..7)
    float loss_part = 0.f;
    for (int p = wave; p < 49; p += 8) {
        int i = p / 7;
        int j = 1 + p % 7;
        float d = 0.f;
        for (int qd = lane; qd < 512; qd += 64) {
            int t = qd >> 6, k = qd & 63;
            d += comp[t * 512 + i * 64 + k] * comp[t * 512 + j * 64 + k];
        }
#pragma unroll
        for (int off = 32; off > 0; off >>= 1) d += __shfl_xor(d, off, 64);
        float ni = norm_s[i], nj = norm_s[j];
        float dot = (d / (ni * nj)) / (sum_s[i] / ni + sum_s[j] / nj);
        loss_part += dot * dot;
    }
    if (lane == 0) red[wave] = loss_part;
    __syncthreads();
    if (tid == 0) {
        float tot = 0.f;
        for (int w = 0; w < 8; ++w) tot += red[w];
        out[4096] = tot * (1.f / 49.f);
    }
}

extern "C" void kernel_launch(void* const* d_in, const int* in_sizes, int n_in,
                              void* d_out, int out_size, void* d_ws, size_t ws_size,
                              hipStream_t stream) {
    const float* x    = (const float*)d_in[0];
    const float* ln1w = (const float*)d_in[1];
    const float* ln1b = (const float*)d_in[2];
    const float* w1   = (const float*)d_in[3];
    const float* b1   = (const float*)d_in[4];
    const float* w2   = (const float*)d_in[5];
    const float* b2   = (const float*)d_in[6];
    const float* lnfw = (const float*)d_in[7];
    const float* lnfb = (const float*)d_in[8];
    // d_in[9] = padded_node_mask (all True by construction; unused)
    const int* node_idx = (const int*)d_in[10];
    float* out = (float*)d_out;

    char* wsb = (char*)d_ws;
    int*   cnt   = (int*)(wsb + O_CNT);
    int*   list  = (int*)(wsb + O_LIST);
    float* csum  = (float*)(wsb + O_CSUM);
    float* czero = (float*)(wsb + O_CZERO);
    float* w1t   = (float*)(wsb + O_W1T);

    hipMemsetAsync(cnt, 0, NBINS * sizeof(int), stream);
    hipMemsetAsync(csum, 0, NBINS * CDIM * sizeof(float), stream);

    bin_kernel<<<(TT * NTOK + 255) / 256, 256, 0, stream>>>(node_idx, cnt, list);
    prep_kernel<<<(DD * EDIM + 255) / 256, 256, 0, stream>>>(w1, b1, w2, w1t, czero);
    main_kernel<<<NBINS * BLOCKS_PER_BIN, 256, 0, stream>>>(
        x, ln1w, ln1b, w1t, b1, w2, cnt, list, csum);
    fin_kernel<<<1, 512, 0, stream>>>(csum, cnt, czero, b2, lnfw, lnfb, out);
}

// Round 2
// 351.029 us; speedup vs baseline: 5.3418x; 5.3418x over previous
//
#include <hip/hip_runtime.h>
#include <math.h>

// Problem constants
#define TT 8
#define NTOK 32768
#define DD 128
#define LCOMP 8
#define GSZ 8192
#define CDIM 64
#define EDIM 128
#define NPART 32

#define TOKB 64                      // tokens per block
#define NBLK (TT*NTOK/TOKB)          // 4096

// workspace byte offsets
#define O_CZERO 0                            // 64 f32
#define O_W2BT  256                          // 64*128 bf16 = 16KB  [k][j]
#define O_W1BT  (256 + EDIM*CDIM*2)          // 128*128 bf16 = 32KB [j][d] swizzled
#define O_CSUMP (O_W1BT + DD*EDIM*2)         // 32*64*64 f32 = 512KB

typedef __attribute__((ext_vector_type(8))) short bf16x8;
typedef __attribute__((ext_vector_type(4))) float f32x4;

__device__ __forceinline__ ushort f2bf(float f) {
    union { float f; uint u; } c; c.f = f;
    uint u = c.u;
    return (ushort)((u + 0x7FFFu + ((u >> 16) & 1u)) >> 16);
}

// gelu via Abramowitz-Stegun 7.1.26 erf (|eps| <= 1.5e-7)
__device__ __forceinline__ float gelu_f(float a) {
    float x = a * 0.70710678118654752f;
    float ax = fabsf(x);
    float t = 1.0f / (1.0f + 0.3275911f * ax);
    float p = t * (0.254829592f + t * (-0.284496736f + t * (1.421413741f +
              t * (-1.453152027f + t * 1.061405429f))));
    float e = __expf(-x * x);
    float er = copysignf(1.0f - p * e, x);
    return 0.5f * a * (1.0f + er);
}

__device__ __forceinline__ void gl_lds16(const void* g, void* l) {
    __builtin_amdgcn_global_load_lds(
        (const __attribute__((address_space(1))) void*)g,
        (__attribute__((address_space(3))) void*)l, 16, 0, 0);
}

// ---------------- prep: bf16 transposed weights (+swizzle for w1), czero ----
__global__ void prep_kernel(const float* __restrict__ w1, const float* __restrict__ b1,
                            const float* __restrict__ w2,
                            ushort* __restrict__ w1bt, ushort* __restrict__ w2bt,
                            float* __restrict__ czero) {
    int gid = blockIdx.x * 256 + threadIdx.x;
    if (gid < DD * EDIM) {                 // w1bt[j][d], 16B-chunk XOR swizzled by (j&7)
        int j = gid >> 7, d = gid & 127;
        int slot = (d >> 3) ^ (j & 7);
        w1bt[j * 128 + slot * 8 + (d & 7)] = f2bf(w1[d * EDIM + j]);
    }
    if (gid < EDIM * CDIM) {               // w2bt[k][j], linear
        int k = gid >> 7, jj = gid & 127;
        w2bt[k * 128 + jj] = f2bf(w2[jj * CDIM + k]);
    }
    if (gid < CDIM) {
        float a2 = 0.f;
        for (int dd = 0; dd < EDIM; ++dd)
            a2 += gelu_f(b1[dd]) * w2[dd * CDIM + gid];
        czero[gid] = a2;
    }
}

// ---------------- main: stage -> LN -> MFMA MLP -> scatter-accumulate -------
__global__ __launch_bounds__(256, 2)
void main_kernel(const float* __restrict__ x,
                 const float* __restrict__ ln1w, const float* __restrict__ ln1b,
                 const float* __restrict__ b1g,
                 const ushort* __restrict__ w1bt, const ushort* __restrict__ w2bt,
                 const float* __restrict__ czero,
                 const int* __restrict__ node_idx,
                 float* __restrict__ csum_p) {
    __shared__ float  s_x[TOKB * DD];      // 32KB f32 stage; becomes xn(16K)+h(16K) bf16
    __shared__ ushort s_w1[DD * EDIM];     // 32KB
    __shared__ float  s_acc[LCOMP * CDIM]; // 2KB
    __shared__ int    s_l[TOKB];

    const int tid = threadIdx.x;
    const int w   = tid >> 6;
    const int ln  = tid & 63;
    const int bid = blockIdx.x;
    const size_t tokbase = (size_t)bid * TOKB;

    // GEMM2 B-frags straight from global (16KB array, L1/L2-hot)
    bf16x8 b2f[4][4];
#pragma unroll
    for (int kt = 0; kt < 4; ++kt)
#pragma unroll
        for (int ks = 0; ks < 4; ++ks) {
            int krow = kt * 16 + (ln & 15);
            b2f[kt][ks] = *(const bf16x8*)(w2bt + krow * EDIM + ks * 32 + (ln >> 4) * 8);
        }

    s_acc[tid] = 0.f; s_acc[tid + 256] = 0.f;
    if (tid < TOKB) s_l[tid] = node_idx[tokbase + tid] >> 13;

    // stage x (source pre-swizzled per-lane so linear LDS ends up swizzled) + w1 (ws pre-swizzled)
    {
        const char* xg = (const char*)(x + tokbase * DD);
        const char* wg = (const char*)w1bt;
        char* lx = (char*)s_x;
        char* lw = (char*)s_w1;
#pragma unroll
        for (int sx = 0; sx < 8; ++sx) {
            int off  = (w * 8 + sx) * 1024 + ln * 16;
            int row  = off >> 9;
            int slot = (off >> 4) & 31;
            int sc   = slot ^ (row & 7);
            gl_lds16(xg + row * 512 + sc * 16, lx + off);
            gl_lds16(wg + off, lw + off);
        }
    }
    __syncthreads();

    // ---- LayerNorm: row = w*16 + (ln&15); 4 lanes/row via cs = ln>>4 ----
    const int row = w * 16 + (ln & 15);
    const int cs  = ln >> 4;
    float v[32];
#pragma unroll
    for (int sx = 0; sx < 8; ++sx) {
        int slot = (cs * 8 + sx) ^ (row & 7);
        float4 f = *(const float4*)((const char*)s_x + row * 512 + slot * 16);
        v[sx*4+0]=f.x; v[sx*4+1]=f.y; v[sx*4+2]=f.z; v[sx*4+3]=f.w;
    }
    {
        float s = 0.f, q = 0.f;
#pragma unroll
        for (int i2 = 0; i2 < 32; ++i2) { s += v[i2]; q += v[i2]*v[i2]; }
        s += __shfl_xor(s, 16, 64); q += __shfl_xor(q, 16, 64);
        s += __shfl_xor(s, 32, 64); q += __shfl_xor(q, 32, 64);
        float m   = s * (1.f/128.f);
        float var = q * (1.f/128.f) - m*m;
        float rs  = rsqrtf(var + 1e-5f);
#pragma unroll
        for (int sx = 0; sx < 8; ++sx) {
            float4 w4 = *(const float4*)(ln1w + cs*32 + sx*4);
            float4 b4 = *(const float4*)(ln1b + cs*32 + sx*4);
            v[sx*4+0] = (v[sx*4+0]-m)*rs*w4.x + b4.x;
            v[sx*4+1] = (v[sx*4+1]-m)*rs*w4.y + b4.y;
            v[sx*4+2] = (v[sx*4+2]-m)*rs*w4.z + b4.z;
            v[sx*4+3] = (v[sx*4+3]-m)*rs*w4.w + b4.w;
        }
    }

    // GEMM1 B-frags from LDS (w1 staged); wave owns j in [32w, 32w+32)
    bf16x8 b1f[2][4];
#pragma unroll
    for (int jt = 0; jt < 2; ++jt)
#pragma unroll
        for (int ks = 0; ks < 4; ++ks) {
            int jrow = w * 32 + jt * 16 + (ln & 15);
            int slot = (ks * 4 + (ln >> 4)) ^ (jrow & 7);
            b1f[jt][ks] = *(const bf16x8*)((const char*)s_w1 + jrow * 256 + slot * 16);
        }
    float b1v0 = b1g[w * 32 + (ln & 15)];
    float b1v1 = b1g[w * 32 + 16 + (ln & 15)];

    __syncthreads();   // all f32 x reads complete before overwrite

    ushort* xn = (ushort*)s_x;            // bytes [0, 16K)
    ushort* hb = (ushort*)s_x + TOKB*DD;  // bytes [16K, 32K)
#pragma unroll
    for (int u = 0; u < 4; ++u) {         // write xn bf16, swizzled
        uint4 pk;
        pk.x = f2bf(v[u*8+0]) | ((uint)f2bf(v[u*8+1]) << 16);
        pk.y = f2bf(v[u*8+2]) | ((uint)f2bf(v[u*8+3]) << 16);
        pk.z = f2bf(v[u*8+4]) | ((uint)f2bf(v[u*8+5]) << 16);
        pk.w = f2bf(v[u*8+6]) | ((uint)f2bf(v[u*8+7]) << 16);
        int slot = (cs * 4 + u) ^ (row & 7);
        *(uint4*)((char*)xn + row * 256 + slot * 16) = pk;
    }
    __syncthreads();   // xn visible

    // ---- GEMM1: A = xn[64x128], B = w1[128x128]; wave: all tokens x 32 j ----
#pragma unroll
    for (int tt = 0; tt < 4; ++tt) {
        bf16x8 a4[4];
        int ar = tt * 16 + (ln & 15);
#pragma unroll
        for (int ks = 0; ks < 4; ++ks) {
            int slot = (ks * 4 + (ln >> 4)) ^ (ar & 7);
            a4[ks] = *(const bf16x8*)((const char*)xn + ar * 256 + slot * 16);
        }
        f32x4 ac0 = {0.f,0.f,0.f,0.f}, ac1 = {0.f,0.f,0.f,0.f};
#pragma unroll
        for (int ks = 0; ks < 4; ++ks) {
            ac0 = __builtin_amdgcn_mfma_f32_16x16x32_bf16(a4[ks], b1f[0][ks], ac0, 0, 0, 0);
            ac1 = __builtin_amdgcn_mfma_f32_16x16x32_bf16(a4[ks], b1f[1][ks], ac1, 0, 0, 0);
        }
        int hrb = tt * 16 + (ln >> 4) * 4;
        int j0  = w * 32 + (ln & 15);
        int j1  = j0 + 16;
#pragma unroll
        for (int r = 0; r < 4; ++r) {
            float h0 = gelu_f(ac0[r] + b1v0);
            float h1 = gelu_f(ac1[r] + b1v1);
            int hrow = hrb + r;
            int sl0 = (j0 >> 3) ^ (hrow & 7);
            int sl1 = (j1 >> 3) ^ (hrow & 7);
            *(ushort*)((char*)hb + hrow*256 + sl0*16 + (j0 & 7)*2) = f2bf(h0);
            *(ushort*)((char*)hb + hrow*256 + sl1*16 + (j1 & 7)*2) = f2bf(h1);
        }
    }
    __syncthreads();   // h complete

    // ---- GEMM2: A = h[16x128] (tile = wave), B = w2[128x64]; scatter ----
    {
        bf16x8 a4[4];
        int ar = w * 16 + (ln & 15);
#pragma unroll
        for (int ks = 0; ks < 4; ++ks) {
            int slot = (ks * 4 + (ln >> 4)) ^ (ar & 7);
            a4[ks] = *(const bf16x8*)((const char*)hb + ar * 256 + slot * 16);
        }
        f32x4 acc0 = {0.f,0.f,0.f,0.f}, acc1 = {0.f,0.f,0.f,0.f};
        f32x4 acc2 = {0.f,0.f,0.f,0.f}, acc3 = {0.f,0.f,0.f,0.f};
#pragma unroll
        for (int ks = 0; ks < 4; ++ks) {
            acc0 = __builtin_amdgcn_mfma_f32_16x16x32_bf16(a4[ks], b2f[0][ks], acc0, 0, 0, 0);
            acc1 = __builtin_amdgcn_mfma_f32_16x16x32_bf16(a4[ks], b2f[1][ks], acc1, 0, 0, 0);
            acc2 = __builtin_amdgcn_mfma_f32_16x16x32_bf16(a4[ks], b2f[2][ks], acc2, 0, 0, 0);
            acc3 = __builtin_amdgcn_mfma_f32_16x16x32_bf16(a4[ks], b2f[3][ks], acc3, 0, 0, 0);
        }
        int tok0 = w * 16 + (ln >> 4) * 4;
        int l0 = s_l[tok0+0], l1 = s_l[tok0+1], l2 = s_l[tok0+2], l3 = s_l[tok0+3];
#pragma unroll
        for (int kt = 0; kt < 4; ++kt) {
            f32x4 a = (kt==0)?acc0:(kt==1)?acc1:(kt==2)?acc2:acc3;
            int k = kt * 16 + (ln & 15);
            float czk = czero[k];
            atomicAdd(&s_acc[l0 * CDIM + k], a[0] - czk);
            atomicAdd(&s_acc[l1 * CDIM + k], a[1] - czk);
            atomicAdd(&s_acc[l2 * CDIM + k], a[2] - czk);
            atomicAdd(&s_acc[l3 * CDIM + k], a[3] - czk);
        }
    }
    __syncthreads();

    {   // flush block accumulator -> partial buffers
        int t8 = (bid >> 9) * LCOMP;
        int p  = bid & (NPART - 1);
#pragma unroll
        for (int i2 = 0; i2 < 2; ++i2) {
            int idx = tid + i2 * 256;
            int l = idx >> 6, k = idx & 63;
            atomicAdd(&csum_p[(p * 64 + t8 + l) * 64 + k], s_acc[idx]);
        }
    }
}

// ---------------- finalize: reduce partials, comp, LN(512), ortho loss ------
__global__ void fin_kernel(const float* __restrict__ csum_p, const float* __restrict__ czero,
                           const float* __restrict__ b2,
                           const float* __restrict__ lnfw, const float* __restrict__ lnfb,
                           float* __restrict__ out) {
    __shared__ float comp[TT * LCOMP * CDIM];
    __shared__ float norm_s[LCOMP], sum_s[LCOMP], red[8];
    int tid = threadIdx.x;

    for (int idx = tid; idx < TT * LCOMP * CDIM; idx += 512) {
        int bin = idx >> 6, k = idx & 63;
        float s = 0.f;
        for (int p = 0; p < NPART; ++p) s += csum_p[(p * 64 + bin) * 64 + k];
        comp[idx] = s * (1.f / GSZ) + czero[k] + b2[k];
    }
    __syncthreads();

    int wave = tid >> 6, lane = tid & 63;

    {   // per-t LayerNorm over 512
        int t = wave;
        float s = 0.f, q = 0.f;
        for (int e = lane; e < 512; e += 64) {
            float v = comp[t * 512 + e];
            s += v; q += v * v;
        }
#pragma unroll
        for (int off = 32; off > 0; off >>= 1) {
            s += __shfl_xor(s, off, 64);
            q += __shfl_xor(q, off, 64);
        }
        float m = s * (1.f / 512.f);
        float var = q * (1.f / 512.f) - m * m;
        float rs = rsqrtf(var + 1e-5f);
        for (int e = lane; e < 512; e += 64) {
            float v = comp[t * 512 + e];
            out[t * 512 + e] = (v - m) * rs * lnfw[e] + lnfb[e];
        }
    }

    {   // per-l norm and sum of f[l]
        int l = wave;
        float s2 = 0.f, s1 = 0.f;
        for (int qd = lane; qd < 512; qd += 64) {
            int t = qd >> 6, k = qd & 63;
            float v = comp[t * 512 + l * 64 + k];
            s2 += v * v; s1 += v;
        }
#pragma unroll
        for (int off = 32; off > 0; off >>= 1) {
            s2 += __shfl_xor(s2, off, 64);
            s1 += __shfl_xor(s1, off, 64);
        }
        if (lane == 0) { norm_s[l] = sqrtf(s2); sum_s[l] = s1; }
    }
    __syncthreads();

    float loss_part = 0.f;
    for (int p = wave; p < 49; p += 8) {
        int i = p / 7, j = 1 + p % 7;
        float d = 0.f;
        for (int qd = lane; qd < 512; qd += 64) {
            int t = qd >> 6, k = qd & 63;
            d += comp[t * 512 + i * 64 + k] * comp[t * 512 + j * 64 + k];
        }
#pragma unroll
        for (int off = 32; off > 0; off >>= 1) d += __shfl_xor(d, off, 64);
        float ni = norm_s[i], nj = norm_s[j];
        float dot = (d / (ni * nj)) / (sum_s[i] / ni + sum_s[j] / nj);
        loss_part += dot * dot;
    }
    if (lane == 0) red[wave] = loss_part;
    __syncthreads();
    if (tid == 0) {
        float tot = 0.f;
        for (int w2_ = 0; w2_ < 8; ++w2_) tot += red[w2_];
        out[4096] = tot * (1.f / 49.f);
    }
}

extern "C" void kernel_launch(void* const* d_in, const int* in_sizes, int n_in,
                              void* d_out, int out_size, void* d_ws, size_t ws_size,
                              hipStream_t stream) {
    const float* x    = (const float*)d_in[0];
    const float* ln1w = (const float*)d_in[1];
    const float* ln1b = (const float*)d_in[2];
    const float* w1   = (const float*)d_in[3];
    const float* b1   = (const float*)d_in[4];
    const float* w2   = (const float*)d_in[5];
    const float* b2   = (const float*)d_in[6];
    const float* lnfw = (const float*)d_in[7];
    const float* lnfb = (const float*)d_in[8];
    const int* node_idx = (const int*)d_in[10];
    float* out = (float*)d_out;

    char* wsb = (char*)d_ws;
    float*  czero = (float*)(wsb + O_CZERO);
    ushort* w2bt  = (ushort*)(wsb + O_W2BT);
    ushort* w1bt  = (ushort*)(wsb + O_W1BT);
    float*  csum_p = (float*)(wsb + O_CSUMP);

    hipMemsetAsync(csum_p, 0, NPART * 64 * 64 * sizeof(float), stream);
    prep_kernel<<<64, 256, 0, stream>>>(w1, b1, w2, w1bt, w2bt, czero);
    main_kernel<<<NBLK, 256, 0, stream>>>(x, ln1w, ln1b, b1, w1bt, w2bt, czero,
                                          node_idx, csum_p);
    fin_kernel<<<1, 512, 0, stream>>>(csum_p, czero, b2, lnfw, lnfb, out);
}